// Round 5
// baseline (52.526 us; speedup 1.0000x reference)
//
#include <hip/hip_runtime.h>
#include <hip/hip_bf16.h>
#include <stdint.h>

// Mahalanobis: out[i] = delta_i @ S_inv @ delta_i^T, delta = x - x_fit
// N=65536, D=256.
// Round 4 -> 5: VGPR stayed 48 across rounds 2-4 even with 64 asm-forced B
// regs => compiler parks B in AGPRs (unified file) and B residency was never
// the problem. New theory: STAGING is VGPR-starved - 16 loads/thread cycled
// through a ~48-reg window => shallow MLP, latency-bound streaming at 60% of
// achievable BW. Fix: issue all 16 staging loads up-front as opaque asm defs
// into explicit f32x4 regs (64 VGPR forced live), one vmcnt(0)+sched_barrier,
// then convert+write. B loads back to plain C++ (compiler AGPRs them).

#define D 256
#define BLOCK_T 512           // 8 waves
#define ROWS_PER_BLOCK 64
#define LDS_STRIDE 272        // 256 + 16 pad: spreads ds_read_b128 over banks

typedef __attribute__((ext_vector_type(4))) float f32x4;
typedef __attribute__((ext_vector_type(8))) short bf16x8;

static __device__ __forceinline__ unsigned short f2bf(float f) {
    union { float f; uint32_t u; } v; v.f = f;
    uint32_t u = v.u;
    return (unsigned short)((u + 0x7FFFu + ((u >> 16) & 1u)) >> 16);
}
static __device__ __forceinline__ float bf2f(unsigned short s) {
    union { uint32_t u; float f; } v; v.u = ((uint32_t)s) << 16;
    return v.f;
}

// Opaque 16B global load: forces the result to be a live VGPR def that the
// scheduler cannot re-sink or rematerialize.
static __device__ __forceinline__ f32x4 gload4f(const float* p) {
    f32x4 r;
    asm volatile("global_load_dwordx4 %0, %1, off"
                 : "=v"(r) : "v"(p));
    return r;
}

// S_inv fp32 -> bf16 (row-major; S is symmetric so this is also S^T)
__global__ void prep_S_kernel(const float* __restrict__ S, unsigned short* __restrict__ Sb) {
    int i = (blockIdx.x * 256 + threadIdx.x) * 4;
    f32x4 v = *(const f32x4*)(S + i);
    uint32_t lo = (uint32_t)f2bf(v[0]) | ((uint32_t)f2bf(v[1]) << 16);
    uint32_t hi = (uint32_t)f2bf(v[2]) | ((uint32_t)f2bf(v[3]) << 16);
    *(uint2*)(Sb + i) = make_uint2(lo, hi);
}

__global__ __launch_bounds__(BLOCK_T, 2) void mahal_kernel(
    const float* __restrict__ x, const float* __restrict__ xf,
    const unsigned short* __restrict__ Sb, float* __restrict__ out)
{
    __shared__ unsigned short ld[ROWS_PER_BLOCK * LDS_STRIDE]; // 34816 B
    __shared__ float psum[8 * ROWS_PER_BLOCK];                 // 2048 B

    const int t    = threadIdx.x;
    const int w    = t >> 6;      // wave 0..7: owns cols [w*32, w*32+32)
    const int lane = t & 63;
    const int lo4  = lane & 15;
    const int hi2  = lane >> 4;
    const int blockRow = blockIdx.x * ROWS_PER_BLOCK;

    // ---- staging loads: ALL 16 issued up-front (16-deep MLP per thread) ----
    const int lrow0 = t >> 5;          // 0..15
    const int col   = (t & 31) * 8;    // 0..248
    f32x4 xa[4], xb[4], fa[4], fb[4];
    #pragma unroll
    for (int i = 0; i < 4; ++i) {
        const int g = (blockRow + i * 16 + lrow0) * D + col;
        xa[i] = gload4f(x  + g);
        xb[i] = gload4f(x  + g + 4);
        fa[i] = gload4f(xf + g);
        fb[i] = gload4f(xf + g + 4);
    }

    // ---- B fragments: plain loads; compiler keeps them in AGPRs ----
    // B[k][n] = S[k][n] = S[n][k] (symmetric) -> row n contiguous along k
    bf16x8 b0[8], b1[8];
    {
        const unsigned short* Sp = Sb + (w * 32 + lo4) * D + hi2 * 8;
        #pragma unroll
        for (int kb = 0; kb < 8; ++kb) {
            b0[kb] = *(const bf16x8*)(Sp + kb * 32);
            b1[kb] = *(const bf16x8*)(Sp + 16 * D + kb * 32);
        }
    }

    // wait for the asm staging loads, then fence the scheduler (rule #18:
    // VALU consumers of asm-def'd regs can otherwise hoist above the wait)
    asm volatile("s_waitcnt vmcnt(0)" ::: "memory");
    __builtin_amdgcn_sched_barrier(0);

    // ---- convert + write delta (bf16) to LDS ----
    #pragma unroll
    for (int i = 0; i < 4; ++i) {
        bf16x8 o;
        o[0] = (short)f2bf(xa[i][0] - fa[i][0]);
        o[1] = (short)f2bf(xa[i][1] - fa[i][1]);
        o[2] = (short)f2bf(xa[i][2] - fa[i][2]);
        o[3] = (short)f2bf(xa[i][3] - fa[i][3]);
        o[4] = (short)f2bf(xb[i][0] - fb[i][0]);
        o[5] = (short)f2bf(xb[i][1] - fb[i][1]);
        o[6] = (short)f2bf(xb[i][2] - fb[i][2]);
        o[7] = (short)f2bf(xb[i][3] - fb[i][3]);
        *(bf16x8*)(&ld[(i * 16 + lrow0) * LDS_STRIDE + col]) = o;
    }

    __syncthreads();

    // ---- 4 row-tiles of 16; each wave computes T over its 32 cols ----
    #pragma unroll
    for (int rt = 0; rt < 4; ++rt) {
        f32x4 acc0 = (f32x4){0.f, 0.f, 0.f, 0.f};
        f32x4 acc1 = (f32x4){0.f, 0.f, 0.f, 0.f};
        const unsigned short* A = &ld[(rt * 16 + lo4) * LDS_STRIDE + hi2 * 8];
        #pragma unroll
        for (int kb = 0; kb < 8; ++kb) {
            bf16x8 a = *(const bf16x8*)(A + kb * 32);
            acc0 = __builtin_amdgcn_mfma_f32_16x16x32_bf16(a, b0[kb], acc0, 0, 0, 0);
            acc1 = __builtin_amdgcn_mfma_f32_16x16x32_bf16(a, b1[kb], acc1, 0, 0, 0);
        }

        // epilogue: partial row-sums over this wave's 32 cols
        // C/D layout: col = lane&15, row = (lane>>4)*4 + reg
        const int c0 = w * 32 + lo4;
        const int c1 = w * 32 + 16 + lo4;
        float pr[4];
        #pragma unroll
        for (int r = 0; r < 4; ++r) {
            const int row = rt * 16 + hi2 * 4 + r;
            pr[r] = acc0[r] * bf2f(ld[row * LDS_STRIDE + c0])
                  + acc1[r] * bf2f(ld[row * LDS_STRIDE + c1]);
        }
        #pragma unroll
        for (int m = 1; m < 16; m <<= 1) {
            #pragma unroll
            for (int r = 0; r < 4; ++r) pr[r] += __shfl_xor(pr[r], m, 64);
        }
        if (lo4 == 0) {
            #pragma unroll
            for (int r = 0; r < 4; ++r)
                psum[w * ROWS_PER_BLOCK + rt * 16 + hi2 * 4 + r] = pr[r];
        }
    }
    __syncthreads();

    // ---- combine the 8 column-slice partials per row ----
    if (t < ROWS_PER_BLOCK) {
        float s = 0.f;
        #pragma unroll
        for (int ww = 0; ww < 8; ++ww) s += psum[ww * ROWS_PER_BLOCK + t];
        out[blockRow + t] = s;
    }
}

extern "C" void kernel_launch(void* const* d_in, const int* in_sizes, int n_in,
                              void* d_out, int out_size, void* d_ws, size_t ws_size,
                              hipStream_t stream) {
    const float* x  = (const float*)d_in[0];
    const float* xf = (const float*)d_in[1];
    const float* S  = (const float*)d_in[2];
    float* out = (float*)d_out;
    unsigned short* Sb = (unsigned short*)d_ws;  // 65536 * 2B = 128 KB scratch

    prep_S_kernel<<<(D * D) / (256 * 4), 256, 0, stream>>>(S, Sb);

    const int nRows = in_sizes[0] / D;           // 65536
    mahal_kernel<<<nRows / ROWS_PER_BLOCK, BLOCK_T, 0, stream>>>(x, xf, Sb, out);
}

// Round 6
// 35.916 us; speedup vs baseline: 1.4625x; 1.4625x over previous
//
#include <hip/hip_runtime.h>
#include <hip/hip_bf16.h>
#include <stdint.h>

// Mahalanobis: out[i] = delta_i @ S_inv @ delta_i^T, delta = x - x_fit
// N=65536, D=256.
// Round 5 -> 6: (1) persistent blocks with an in-block software pipeline:
// grid=256, 4 tiles of 64 rows per block; tile j+1's loads (opaque asm) are
// issued before computing tile j, and barriers are raw s_barrier + manual
// lgkmcnt(0) ONLY (no vmcnt drain at the barrier) so prefetch loads stay in
// flight across compute - the memory pipe never idles on compute phases.
// (2) transposed MFMA epilogue: mfma(S_frag, delta_frag) computes T^T, so
// each delta-row lives in lane&15; epilogue = 2 ds_read_b64 + 8 FMA + 2
// shuffles per rt instead of 8 scalar LDS reads + a 4x4 shuffle tree.

#define D 256
#define BLOCK_T 512           // 8 waves
#define ROWS_PER_TILE 64
#define NT 4                  // tiles per block; grid = 65536/(4*64) = 256
#define LDS_STRIDE 272

typedef __attribute__((ext_vector_type(4))) float f32x4;
typedef __attribute__((ext_vector_type(8))) short bf16x8;
typedef __attribute__((ext_vector_type(4))) short bf16x4;

static __device__ __forceinline__ unsigned short f2bf(float f) {
    union { float f; uint32_t u; } v; v.f = f;
    uint32_t u = v.u;
    return (unsigned short)((u + 0x7FFFu + ((u >> 16) & 1u)) >> 16);
}
static __device__ __forceinline__ float bf2f(unsigned short s) {
    union { uint32_t u; float f; } v; v.u = ((uint32_t)s) << 16;
    return v.f;
}

// Opaque 16B global load: fixed issue point (cannot be sunk to its use).
static __device__ __forceinline__ f32x4 gload4f(const float* p) {
    f32x4 r;
    asm volatile("global_load_dwordx4 %0, %1, off" : "=v"(r) : "v"(p));
    return r;
}

// S_inv fp32 -> bf16 (row-major; S is symmetric so this is also S^T)
__global__ void prep_S_kernel(const float* __restrict__ S, unsigned short* __restrict__ Sb) {
    int i = (blockIdx.x * 256 + threadIdx.x) * 4;
    f32x4 v = *(const f32x4*)(S + i);
    uint32_t lo = (uint32_t)f2bf(v[0]) | ((uint32_t)f2bf(v[1]) << 16);
    uint32_t hi = (uint32_t)f2bf(v[2]) | ((uint32_t)f2bf(v[3]) << 16);
    *(uint2*)(Sb + i) = make_uint2(lo, hi);
}

__global__ __launch_bounds__(BLOCK_T, 2) void mahal_kernel(
    const float* __restrict__ x, const float* __restrict__ xf,
    const unsigned short* __restrict__ Sb, float* __restrict__ out)
{
    __shared__ unsigned short ld[ROWS_PER_TILE * LDS_STRIDE]; // 34816 B
    __shared__ float psum[8 * ROWS_PER_TILE];                 // 2048 B

    const int t    = threadIdx.x;
    const int w    = t >> 6;      // wave 0..7: owns cols [w*32, w*32+32)
    const int lane = t & 63;
    const int lo4  = lane & 15;
    const int hi2  = lane >> 4;
    const int lrow0 = t >> 5;          // staging: 0..15
    const int col   = (t & 31) * 8;    // staging: 0..248
    const int blockRow0 = blockIdx.x * (NT * ROWS_PER_TILE);

    // ---- S fragments for this wave's 32-col slice (plain loads -> AGPRs).
    // Used as the MFMA *A*-operand: A[i][k] = S[w*32 + nb*16 + i][k].
    bf16x8 b0[8], b1[8];
    {
        const unsigned short* Sp = Sb + (w * 32 + lo4) * D + hi2 * 8;
        #pragma unroll
        for (int kb = 0; kb < 8; ++kb) {
            b0[kb] = *(const bf16x8*)(Sp + kb * 32);
            b1[kb] = *(const bf16x8*)(Sp + 16 * D + kb * 32);
        }
    }

    // ---- prologue: issue tile 0 staging loads ----
    f32x4 xa[4], xb[4], fa[4], fb[4];
    #pragma unroll
    for (int i = 0; i < 4; ++i) {
        const int g = (blockRow0 + i * 16 + lrow0) * D + col;
        xa[i] = gload4f(x + g);
        xb[i] = gload4f(x + g + 4);
        fa[i] = gload4f(xf + g);
        fb[i] = gload4f(xf + g + 4);
    }

    for (int j = 0; j < NT; ++j) {
        // tile j's staged registers arrived (asm loads: we own the wait)
        asm volatile("s_waitcnt vmcnt(0)" ::: "memory");
        __builtin_amdgcn_sched_barrier(0);

        if (j > 0) {
            // (a) all waves done reading LDS (tile j-1 compute + psum writes
            // retired via lgkmcnt). No vmcnt drain here.
            asm volatile("s_waitcnt lgkmcnt(0)" ::: "memory");
            __builtin_amdgcn_s_barrier();
            // combine tile j-1 partials while others start converting
            if (t < ROWS_PER_TILE) {
                float s = 0.f;
                #pragma unroll
                for (int ww = 0; ww < 8; ++ww) s += psum[ww * ROWS_PER_TILE + t];
                out[blockRow0 + (j - 1) * ROWS_PER_TILE + t] = s;
            }
        }

        // ---- convert tile j -> bf16 delta in LDS ----
        #pragma unroll
        for (int i = 0; i < 4; ++i) {
            bf16x8 o;
            o[0] = (short)f2bf(xa[i][0] - fa[i][0]);
            o[1] = (short)f2bf(xa[i][1] - fa[i][1]);
            o[2] = (short)f2bf(xa[i][2] - fa[i][2]);
            o[3] = (short)f2bf(xa[i][3] - fa[i][3]);
            o[4] = (short)f2bf(xb[i][0] - fb[i][0]);
            o[5] = (short)f2bf(xb[i][1] - fb[i][1]);
            o[6] = (short)f2bf(xb[i][2] - fb[i][2]);
            o[7] = (short)f2bf(xb[i][3] - fb[i][3]);
            *(bf16x8*)(&ld[(i * 16 + lrow0) * LDS_STRIDE + col]) = o;
        }

        // ---- issue tile j+1 loads: they fly across the barrier, under
        // tile j's compute (counted-vmcnt principle: never drain in-loop) ----
        if (j + 1 < NT) {
            #pragma unroll
            for (int i = 0; i < 4; ++i) {
                const int g = (blockRow0 + (j + 1) * ROWS_PER_TILE + i * 16 + lrow0) * D + col;
                xa[i] = gload4f(x + g);
                xb[i] = gload4f(x + g + 4);
                fa[i] = gload4f(xf + g);
                fb[i] = gload4f(xf + g + 4);
            }
        }

        // (b) LDS writes visible. lgkmcnt only - prefetch stays in flight.
        asm volatile("s_waitcnt lgkmcnt(0)" ::: "memory");
        __builtin_amdgcn_s_barrier();
        __builtin_amdgcn_sched_barrier(0);

        // ---- compute tile j: acc = T^T for this wave's col slice ----
        #pragma unroll
        for (int rt = 0; rt < 4; ++rt) {
            f32x4 acc0 = (f32x4){0.f, 0.f, 0.f, 0.f};
            f32x4 acc1 = (f32x4){0.f, 0.f, 0.f, 0.f};
            const unsigned short* A = &ld[(rt * 16 + lo4) * LDS_STRIDE + hi2 * 8];
            #pragma unroll
            for (int kb = 0; kb < 8; ++kb) {
                bf16x8 a = *(const bf16x8*)(A + kb * 32);
                // swapped operands: D[i][j] = sum_k S[slice_i][k] * delta[row_j][k]
                acc0 = __builtin_amdgcn_mfma_f32_16x16x32_bf16(b0[kb], a, acc0, 0, 0, 0);
                acc1 = __builtin_amdgcn_mfma_f32_16x16x32_bf16(b1[kb], a, acc1, 0, 0, 0);
            }
            // lane lo4 = delta row (rt*16+lo4); reg r of acc_nb holds
            // T[drow][w*32 + nb*16 + hi2*4 + r] -> dot with delta at those cols
            const unsigned short* dr = &ld[(rt * 16 + lo4) * LDS_STRIDE + w * 32 + hi2 * 4];
            bf16x4 d0 = *(const bf16x4*)(dr);
            bf16x4 d1 = *(const bf16x4*)(dr + 16);
            float pr = 0.f;
            #pragma unroll
            for (int r = 0; r < 4; ++r) {
                pr += acc0[r] * bf2f((unsigned short)d0[r]);
                pr += acc1[r] * bf2f((unsigned short)d1[r]);
            }
            // reduce over the 4 hi2 groups holding the same delta row
            pr += __shfl_xor(pr, 16, 64);
            pr += __shfl_xor(pr, 32, 64);
            if (lane < 16)
                psum[w * ROWS_PER_TILE + rt * 16 + lane] = pr;
        }
    }

    // ---- final tile's combine ----
    asm volatile("s_waitcnt lgkmcnt(0)" ::: "memory");
    __builtin_amdgcn_s_barrier();
    if (t < ROWS_PER_TILE) {
        float s = 0.f;
        #pragma unroll
        for (int ww = 0; ww < 8; ++ww) s += psum[ww * ROWS_PER_TILE + t];
        out[blockRow0 + (NT - 1) * ROWS_PER_TILE + t] = s;
    }
}

extern "C" void kernel_launch(void* const* d_in, const int* in_sizes, int n_in,
                              void* d_out, int out_size, void* d_ws, size_t ws_size,
                              hipStream_t stream) {
    const float* x  = (const float*)d_in[0];
    const float* xf = (const float*)d_in[1];
    const float* S  = (const float*)d_in[2];
    float* out = (float*)d_out;
    unsigned short* Sb = (unsigned short*)d_ws;  // 65536 * 2B = 128 KB scratch

    prep_S_kernel<<<(D * D) / (256 * 4), 256, 0, stream>>>(S, Sb);

    const int nRows = in_sizes[0] / D;                      // 65536
    const int nBlocks = nRows / (NT * ROWS_PER_TILE);       // 256
    mahal_kernel<<<nBlocks, BLOCK_T, 0, stream>>>(x, xf, Sb, out);
}